// Round 1
// baseline (1074.417 us; speedup 1.0000x reference)
//
#include <hip/hip_runtime.h>
#include <hip/hip_bf16.h>
#include <cstdint>

#define D_DIM 1024
#define H_DIM 4096
#define E_NUM 8
#define NTOK  8192

#define BM 128
#define BN 128
#define BK 32
#define LDT 56   // padded LDS row stride (elements); 112B = 7*16B keeps b128 aligned

typedef __bf16 bf16;
typedef __bf16 bf16x8 __attribute__((ext_vector_type(8)));
typedef __bf16 bf16x4 __attribute__((ext_vector_type(4)));
typedef float  f32x4  __attribute__((ext_vector_type(4)));

// ---------------- gating ----------------
__global__ __launch_bounds__(64) void gate_kernel(
    const float* __restrict__ x, const float* __restrict__ Wg,
    const float* __restrict__ bg, float* __restrict__ out_probs,
    float* __restrict__ out_idx, int* __restrict__ cnt, int* __restrict__ list)
{
    const int t = blockIdx.x;
    const int l = threadIdx.x;
    double part[E_NUM];
#pragma unroll
    for (int e = 0; e < E_NUM; e++) part[e] = 0.0;
    const float* xr = x + (size_t)t * D_DIM;
#pragma unroll
    for (int i = 0; i < D_DIM / 64; i++) {
        const int d = l + i * 64;
        const float xv = xr[d];
        const float* wr = Wg + (size_t)d * E_NUM;
        float4 w0 = *(const float4*)(wr);
        float4 w1 = *(const float4*)(wr + 4);
        part[0] += (double)xv * (double)w0.x;
        part[1] += (double)xv * (double)w0.y;
        part[2] += (double)xv * (double)w0.z;
        part[3] += (double)xv * (double)w0.w;
        part[4] += (double)xv * (double)w1.x;
        part[5] += (double)xv * (double)w1.y;
        part[6] += (double)xv * (double)w1.z;
        part[7] += (double)xv * (double)w1.w;
    }
#pragma unroll
    for (int e = 0; e < E_NUM; e++) {
        double v = part[e];
        for (int s = 32; s > 0; s >>= 1) v += __shfl_xor(v, s, 64);
        part[e] = v;
    }
    if (l == 0) {
        float logits[E_NUM], probs[E_NUM];
        float m = -3.0e38f;
#pragma unroll
        for (int e = 0; e < E_NUM; e++) {
            logits[e] = (float)(part[e] + (double)bg[e]);
            m = fmaxf(m, logits[e]);
        }
        float s = 0.f;
#pragma unroll
        for (int e = 0; e < E_NUM; e++) { probs[e] = expf(logits[e] - m); s += probs[e]; }
        const float inv = 1.f / s;
        int best = 0; float bp = -1.f;
#pragma unroll
        for (int e = 0; e < E_NUM; e++) {
            probs[e] *= inv;
            if (probs[e] > bp) { bp = probs[e]; best = e; }
        }
#pragma unroll
        for (int e = 0; e < E_NUM; e++) out_probs[(size_t)t * E_NUM + e] = probs[e];
        out_idx[t] = (float)best;
        const int pos = atomicAdd(&cnt[best], 1);
        list[best * NTOK + pos] = t;
    }
}

__global__ void zero_cnt_kernel(int* cnt)
{
    if (threadIdx.x < E_NUM) cnt[threadIdx.x] = 0;
}

__global__ void offsets_kernel(const int* __restrict__ cnt, int* __restrict__ off)
{
    if (threadIdx.x == 0) {
        int a = 0;
        for (int e = 0; e < E_NUM; e++) { off[e] = a; a += cnt[e]; }
    }
}

// gather routed x rows into bf16, contiguous per expert
__global__ __launch_bounds__(256) void gather_kernel(
    const float* __restrict__ x, const int* __restrict__ off,
    const int* __restrict__ cnt, const int* __restrict__ list,
    bf16* __restrict__ Xg)
{
    const int p = blockIdx.x;  // global routed position, 0..NTOK-1
    int e = 0;
    while (e < E_NUM - 1 && p >= off[e] + cnt[e]) e++;
    const int token = list[e * NTOK + (p - off[e])];
    const float* src = x + (size_t)token * D_DIM;
    bf16* dst = Xg + (size_t)p * D_DIM;
    const int t = threadIdx.x;
    float4 v = *(const float4*)(src + t * 4);
    bf16x4 o;
    o[0] = (bf16)v.x; o[1] = (bf16)v.y; o[2] = (bf16)v.z; o[3] = (bf16)v.w;
    *(bf16x4*)(dst + t * 4) = o;
}

// transpose+convert one [K][N] fp32 matrix (per expert) to [N][K] bf16
__global__ __launch_bounds__(256) void transpose_conv_kernel(
    const float* __restrict__ in, bf16* __restrict__ out, int K, int N)
{
    const int e = blockIdx.z;
    const float* src = in + (size_t)e * K * N;
    bf16* dst = out + (size_t)e * K * N;
    __shared__ float T[32][33];
    const int t = threadIdx.x;
    const int ty = t >> 3, tx = t & 7;
    const int k0 = blockIdx.x * 32, n0 = blockIdx.y * 32;
    float4 v = *(const float4*)(src + (size_t)(k0 + ty) * N + n0 + tx * 4);
    T[ty][tx * 4 + 0] = v.x; T[ty][tx * 4 + 1] = v.y;
    T[ty][tx * 4 + 2] = v.z; T[ty][tx * 4 + 3] = v.w;
    __syncthreads();
    bf16x4 o;
    o[0] = (bf16)T[tx * 4 + 0][ty];
    o[1] = (bf16)T[tx * 4 + 1][ty];
    o[2] = (bf16)T[tx * 4 + 2][ty];
    o[3] = (bf16)T[tx * 4 + 3][ty];
    *(bf16x4*)(dst + (size_t)(n0 + ty) * K + k0 + tx * 4) = o;
}

// partial sums of c[e][d] = relu(b1[e]) . W2[e][:,d]
__global__ __launch_bounds__(256) void cpart_kernel(
    const float* __restrict__ W2, const float* __restrict__ b1,
    float* __restrict__ cpart)
{
    const int chunk = blockIdx.x;  // 32 chunks of 128 h-values
    const int e = blockIdx.y;
    const int t = threadIdx.x;
    float acc0 = 0.f, acc1 = 0.f, acc2 = 0.f, acc3 = 0.f;
    for (int hh = 0; hh < H_DIM / 32; hh++) {
        const int h = chunk * (H_DIM / 32) + hh;
        const float rb = fmaxf(b1[(size_t)e * H_DIM + h], 0.f);
        float4 w = *(const float4*)(W2 + ((size_t)e * H_DIM + h) * D_DIM + t * 4);
        acc0 += rb * w.x; acc1 += rb * w.y; acc2 += rb * w.z; acc3 += rb * w.w;
    }
    float* dst = cpart + ((size_t)(e * 32 + chunk)) * D_DIM + t * 4;
    dst[0] = acc0; dst[1] = acc1; dst[2] = acc2; dst[3] = acc3;
}

// c[e][d] -> adj[e][d] = (sum_e' c[e'][d]) - c[e][d]
__global__ __launch_bounds__(256) void cfinal_kernel(
    const float* __restrict__ cpart, const float* __restrict__ b2,
    float* __restrict__ adj)
{
    const int d = blockIdx.x * 256 + threadIdx.x;
    float c[E_NUM];
    float tot = 0.f;
#pragma unroll
    for (int e = 0; e < E_NUM; e++) {
        float s = 0.f;
        for (int ch = 0; ch < 32; ch++) s += cpart[((size_t)(e * 32 + ch)) * D_DIM + d];
        s += b2[(size_t)e * D_DIM + d];
        c[e] = s; tot += s;
    }
#pragma unroll
    for (int e = 0; e < E_NUM; e++) adj[(size_t)e * D_DIM + d] = tot - c[e];
}

// ---------------- grouped GEMM 1: h = relu(Xg @ W1[e] + b1[e]) ----------------
__global__ __launch_bounds__(256) void gemm1_kernel(
    const bf16* __restrict__ Xg, const bf16* __restrict__ W1t,
    const float* __restrict__ b1, const int* __restrict__ cnt,
    const int* __restrict__ off, bf16* __restrict__ Hb)
{
    const int e = blockIdx.z;
    const int ne = cnt[e];
    const int bx = blockIdx.x;
    if (bx * BM >= ne) return;
    const int by = blockIdx.y;
    const int oe = off[e];

    __shared__ bf16 As[BM * LDT];
    __shared__ bf16 Bs[BN * LDT];

    const int t = threadIdx.x;
    const int w = t >> 6, lane = t & 63;
    const int wr = w >> 1, wc = w & 1;
    const int lrow = lane & 15, kq = (lane >> 4) * 8;

    f32x4 acc[4][4];
#pragma unroll
    for (int m = 0; m < 4; m++)
#pragma unroll
        for (int n = 0; n < 4; n++) acc[m][n] = (f32x4){0.f, 0.f, 0.f, 0.f};

    const int srow = t >> 2;          // 0..63 (stage rows srow and srow+64)
    const int scol = (t & 3) * 8;
    const bool av0 = (bx * BM + srow) < ne;
    const bool av1 = (bx * BM + srow + 64) < ne;
    const bf16* aptr0 = Xg + ((size_t)(oe + bx * BM + srow)) * D_DIM + scol;
    const bf16* aptr1 = aptr0 + (size_t)64 * D_DIM;
    const bf16* bptr0 = W1t + ((size_t)e * H_DIM + by * BN + srow) * D_DIM + scol;
    const bf16* bptr1 = bptr0 + (size_t)64 * D_DIM;

    for (int kt = 0; kt < D_DIM / BK; kt++) {
        uint4 a0 = av0 ? *(const uint4*)aptr0 : (uint4){0u, 0u, 0u, 0u};
        uint4 a1 = av1 ? *(const uint4*)aptr1 : (uint4){0u, 0u, 0u, 0u};
        uint4 b0 = *(const uint4*)bptr0;
        uint4 b1v = *(const uint4*)bptr1;
        __syncthreads();
        *(uint4*)&As[srow * LDT + scol] = a0;
        *(uint4*)&As[(srow + 64) * LDT + scol] = a1;
        *(uint4*)&Bs[srow * LDT + scol] = b0;
        *(uint4*)&Bs[(srow + 64) * LDT + scol] = b1v;
        __syncthreads();
        aptr0 += BK; aptr1 += BK; bptr0 += BK; bptr1 += BK;

        bf16x8 af[4], bfr[4];
#pragma unroll
        for (int m = 0; m < 4; m++)
            af[m] = *(const bf16x8*)&As[(wr * 64 + m * 16 + lrow) * LDT + kq];
#pragma unroll
        for (int n = 0; n < 4; n++)
            bfr[n] = *(const bf16x8*)&Bs[(wc * 64 + n * 16 + lrow) * LDT + kq];
#pragma unroll
        for (int m = 0; m < 4; m++)
#pragma unroll
            for (int n = 0; n < 4; n++)
                acc[m][n] = __builtin_amdgcn_mfma_f32_16x16x32_bf16(af[m], bfr[n], acc[m][n], 0, 0, 0);
    }

#pragma unroll
    for (int m = 0; m < 4; m++) {
        const int rb0 = bx * BM + wr * 64 + m * 16 + ((lane >> 4) << 2);
#pragma unroll
        for (int n = 0; n < 4; n++) {
            const int gcol = by * BN + wc * 64 + n * 16 + (lane & 15);
            const float bias = b1[(size_t)e * H_DIM + gcol];
#pragma unroll
            for (int r = 0; r < 4; r++) {
                const int grow = rb0 + r;
                if (grow < ne) {
                    float v = acc[m][n][r] + bias;
                    Hb[((size_t)(oe + grow)) * H_DIM + gcol] = (bf16)fmaxf(v, 0.f);
                }
            }
        }
    }
}

// ---------------- grouped GEMM 2: out = h @ W2[e] + b2[e] + adj[e] ----------------
__global__ __launch_bounds__(256) void gemm2_kernel(
    const bf16* __restrict__ Hb, const bf16* __restrict__ W2t,
    const float* __restrict__ b2, const float* __restrict__ adj,
    const int* __restrict__ cnt, const int* __restrict__ off,
    const int* __restrict__ list, float* __restrict__ out)
{
    const int e = blockIdx.z;
    const int ne = cnt[e];
    const int bx = blockIdx.x;
    if (bx * BM >= ne) return;
    const int by = blockIdx.y;
    const int oe = off[e];

    __shared__ bf16 As[BM * LDT];
    __shared__ bf16 Bs[BN * LDT];

    const int t = threadIdx.x;
    const int w = t >> 6, lane = t & 63;
    const int wr = w >> 1, wc = w & 1;
    const int lrow = lane & 15, kq = (lane >> 4) * 8;

    f32x4 acc[4][4];
#pragma unroll
    for (int m = 0; m < 4; m++)
#pragma unroll
        for (int n = 0; n < 4; n++) acc[m][n] = (f32x4){0.f, 0.f, 0.f, 0.f};

    const int srow = t >> 2;
    const int scol = (t & 3) * 8;
    const bool av0 = (bx * BM + srow) < ne;
    const bool av1 = (bx * BM + srow + 64) < ne;
    const bf16* aptr0 = Hb + ((size_t)(oe + bx * BM + srow)) * H_DIM + scol;
    const bf16* aptr1 = aptr0 + (size_t)64 * H_DIM;
    const bf16* bptr0 = W2t + ((size_t)e * D_DIM + by * BN + srow) * H_DIM + scol;
    const bf16* bptr1 = bptr0 + (size_t)64 * H_DIM;

    for (int kt = 0; kt < H_DIM / BK; kt++) {
        uint4 a0 = av0 ? *(const uint4*)aptr0 : (uint4){0u, 0u, 0u, 0u};
        uint4 a1 = av1 ? *(const uint4*)aptr1 : (uint4){0u, 0u, 0u, 0u};
        uint4 b0 = *(const uint4*)bptr0;
        uint4 b1v = *(const uint4*)bptr1;
        __syncthreads();
        *(uint4*)&As[srow * LDT + scol] = a0;
        *(uint4*)&As[(srow + 64) * LDT + scol] = a1;
        *(uint4*)&Bs[srow * LDT + scol] = b0;
        *(uint4*)&Bs[(srow + 64) * LDT + scol] = b1v;
        __syncthreads();
        aptr0 += BK; aptr1 += BK; bptr0 += BK; bptr1 += BK;

        bf16x8 af[4], bfr[4];
#pragma unroll
        for (int m = 0; m < 4; m++)
            af[m] = *(const bf16x8*)&As[(wr * 64 + m * 16 + lrow) * LDT + kq];
#pragma unroll
        for (int n = 0; n < 4; n++)
            bfr[n] = *(const bf16x8*)&Bs[(wc * 64 + n * 16 + lrow) * LDT + kq];
#pragma unroll
        for (int m = 0; m < 4; m++)
#pragma unroll
            for (int n = 0; n < 4; n++)
                acc[m][n] = __builtin_amdgcn_mfma_f32_16x16x32_bf16(af[m], bfr[n], acc[m][n], 0, 0, 0);
    }

#pragma unroll
    for (int m = 0; m < 4; m++) {
        const int rb0 = bx * BM + wr * 64 + m * 16 + ((lane >> 4) << 2);
#pragma unroll
        for (int n = 0; n < 4; n++) {
            const int gcol = by * BN + wc * 64 + n * 16 + (lane & 15);
            const float badj = b2[(size_t)e * D_DIM + gcol] + adj[(size_t)e * D_DIM + gcol];
#pragma unroll
            for (int r = 0; r < 4; r++) {
                const int grow = rb0 + r;
                if (grow < ne) {
                    const int tok = list[e * NTOK + grow];
                    out[(size_t)tok * D_DIM + gcol] = acc[m][n][r] + badj;
                }
            }
        }
    }
}

extern "C" void kernel_launch(void* const* d_in, const int* in_sizes, int n_in,
                              void* d_out, int out_size, void* d_ws, size_t ws_size,
                              hipStream_t stream)
{
    (void)in_sizes; (void)n_in; (void)out_size; (void)ws_size;
    const float* x  = (const float*)d_in[0];
    const float* Wg = (const float*)d_in[1];
    const float* bg = (const float*)d_in[2];
    const float* W1 = (const float*)d_in[3];
    const float* b1 = (const float*)d_in[4];
    const float* W2 = (const float*)d_in[5];
    const float* b2 = (const float*)d_in[6];

    float* out_comb  = (float*)d_out;
    float* out_probs = out_comb + (size_t)NTOK * D_DIM;
    float* out_idx   = out_probs + (size_t)NTOK * E_NUM;

    char* ws = (char*)d_ws;
    size_t o = 0;
    bf16* W1t = (bf16*)(ws + o); o += (size_t)E_NUM * H_DIM * D_DIM * 2;  // 64MB
    bf16* W2t = (bf16*)(ws + o); o += (size_t)E_NUM * H_DIM * D_DIM * 2;  // 64MB
    bf16* Xg  = (bf16*)(ws + o); o += (size_t)NTOK * D_DIM * 2;           // 16MB
    bf16* Hb  = (bf16*)(ws + o); o += (size_t)NTOK * H_DIM * 2;           // 64MB
    float* cpart = (float*)(ws + o); o += (size_t)E_NUM * 32 * D_DIM * 4; // 1MB
    float* adj   = (float*)(ws + o); o += (size_t)E_NUM * D_DIM * 4;
    int* cnt  = (int*)(ws + o); o += 256;
    int* off  = (int*)(ws + o); o += 256;
    int* list = (int*)(ws + o); o += (size_t)E_NUM * NTOK * 4;            // 256KB

    zero_cnt_kernel<<<1, 64, 0, stream>>>(cnt);
    gate_kernel<<<NTOK, 64, 0, stream>>>(x, Wg, bg, out_probs, out_idx, cnt, list);
    offsets_kernel<<<1, 64, 0, stream>>>(cnt, off);
    gather_kernel<<<NTOK, 256, 0, stream>>>(x, off, cnt, list, Xg);
    transpose_conv_kernel<<<dim3(D_DIM / 32, H_DIM / 32, E_NUM), 256, 0, stream>>>(W1, W1t, D_DIM, H_DIM);
    transpose_conv_kernel<<<dim3(H_DIM / 32, D_DIM / 32, E_NUM), 256, 0, stream>>>(W2, W2t, H_DIM, D_DIM);
    cpart_kernel<<<dim3(32, E_NUM), 256, 0, stream>>>(W2, b1, cpart);
    cfinal_kernel<<<D_DIM / 256, 256, 0, stream>>>(cpart, b2, adj);
    gemm1_kernel<<<dim3(NTOK / BM, H_DIM / BN, E_NUM), 256, 0, stream>>>(Xg, W1t, b1, cnt, off, Hb);
    gemm2_kernel<<<dim3(NTOK / BM, D_DIM / BN, E_NUM), 256, 0, stream>>>(Hb, W2t, b2, adj, cnt, off, list, out_comb);
}

// Round 2
// 972.809 us; speedup vs baseline: 1.1044x; 1.1044x over previous
//
#include <hip/hip_runtime.h>
#include <hip/hip_bf16.h>
#include <cstdint>

#define D_DIM 1024
#define H_DIM 4096
#define E_NUM 8
#define NTOK  8192

#define BM 128
#define BN 128
#define BK 32

typedef __bf16 bf16;
typedef __bf16 bf16x8 __attribute__((ext_vector_type(8)));
typedef __bf16 bf16x4 __attribute__((ext_vector_type(4)));
typedef float  f32x4  __attribute__((ext_vector_type(4)));

// global_load_lds: per-lane global src, wave-uniform LDS base + lane*16B dest
#define GLOAD16(g, l)                                                          \
    __builtin_amdgcn_global_load_lds(                                          \
        (const __attribute__((address_space(1))) void*)(g),                    \
        (__attribute__((address_space(3))) void*)(l), 16, 0, 0)

// ---------------- gating ----------------
__global__ __launch_bounds__(64) void gate_kernel(
    const float* __restrict__ x, const float* __restrict__ Wg,
    const float* __restrict__ bg, float* __restrict__ out_probs,
    float* __restrict__ out_idx, int* __restrict__ cnt, int* __restrict__ list)
{
    const int t = blockIdx.x;
    const int l = threadIdx.x;
    double part[E_NUM];
#pragma unroll
    for (int e = 0; e < E_NUM; e++) part[e] = 0.0;
    const float* xr = x + (size_t)t * D_DIM;
#pragma unroll
    for (int i = 0; i < D_DIM / 64; i++) {
        const int d = l + i * 64;
        const float xv = xr[d];
        const float* wr = Wg + (size_t)d * E_NUM;
        float4 w0 = *(const float4*)(wr);
        float4 w1 = *(const float4*)(wr + 4);
        part[0] += (double)xv * (double)w0.x;
        part[1] += (double)xv * (double)w0.y;
        part[2] += (double)xv * (double)w0.z;
        part[3] += (double)xv * (double)w0.w;
        part[4] += (double)xv * (double)w1.x;
        part[5] += (double)xv * (double)w1.y;
        part[6] += (double)xv * (double)w1.z;
        part[7] += (double)xv * (double)w1.w;
    }
#pragma unroll
    for (int e = 0; e < E_NUM; e++) {
        double v = part[e];
        for (int s = 32; s > 0; s >>= 1) v += __shfl_xor(v, s, 64);
        part[e] = v;
    }
    if (l == 0) {
        float logits[E_NUM], probs[E_NUM];
        float m = -3.0e38f;
#pragma unroll
        for (int e = 0; e < E_NUM; e++) {
            logits[e] = (float)(part[e] + (double)bg[e]);
            m = fmaxf(m, logits[e]);
        }
        float s = 0.f;
#pragma unroll
        for (int e = 0; e < E_NUM; e++) { probs[e] = expf(logits[e] - m); s += probs[e]; }
        const float inv = 1.f / s;
        int best = 0; float bp = -1.f;
#pragma unroll
        for (int e = 0; e < E_NUM; e++) {
            probs[e] *= inv;
            if (probs[e] > bp) { bp = probs[e]; best = e; }
        }
#pragma unroll
        for (int e = 0; e < E_NUM; e++) out_probs[(size_t)t * E_NUM + e] = probs[e];
        out_idx[t] = (float)best;
        const int pos = atomicAdd(&cnt[best], 1);
        list[best * NTOK + pos] = t;
    }
}

__global__ void zero_cnt_kernel(int* cnt)
{
    if (threadIdx.x < E_NUM) cnt[threadIdx.x] = 0;
}

__global__ void offsets_kernel(const int* __restrict__ cnt, int* __restrict__ off)
{
    if (threadIdx.x == 0) {
        int a = 0;
        for (int e = 0; e < E_NUM; e++) { off[e] = a; a += cnt[e]; }
    }
}

// gather routed x rows into bf16, contiguous per expert
__global__ __launch_bounds__(256) void gather_kernel(
    const float* __restrict__ x, const int* __restrict__ off,
    const int* __restrict__ cnt, const int* __restrict__ list,
    bf16* __restrict__ Xg)
{
    const int p = blockIdx.x;
    int e = 0;
    while (e < E_NUM - 1 && p >= off[e] + cnt[e]) e++;
    const int token = list[e * NTOK + (p - off[e])];
    const float* src = x + (size_t)token * D_DIM;
    bf16* dst = Xg + (size_t)p * D_DIM;
    const int t = threadIdx.x;
    float4 v = *(const float4*)(src + t * 4);
    bf16x4 o;
    o[0] = (bf16)v.x; o[1] = (bf16)v.y; o[2] = (bf16)v.z; o[3] = (bf16)v.w;
    *(bf16x4*)(dst + t * 4) = o;
}

// transpose+convert one [K][N] fp32 matrix (per expert) to [N][K] bf16. 64x64 tiles.
__global__ __launch_bounds__(256) void transpose_conv_kernel(
    const float* __restrict__ in, bf16* __restrict__ out, int K, int N)
{
    const int e = blockIdx.z;
    const float* src = in + (size_t)e * K * N;
    bf16* dst = out + (size_t)e * K * N;
    __shared__ float T[64][65];
    const int t = threadIdx.x;
    const int k0 = blockIdx.x * 64, n0 = blockIdx.y * 64;
    {
        const int ty = t >> 4;        // 0..15
        const int tx = (t & 15) * 4;  // 0..60
#pragma unroll
        for (int i = 0; i < 4; i++) {
            float4 v = *(const float4*)(src + (size_t)(k0 + ty + 16 * i) * N + n0 + tx);
            T[ty + 16 * i][tx + 0] = v.x; T[ty + 16 * i][tx + 1] = v.y;
            T[ty + 16 * i][tx + 2] = v.z; T[ty + 16 * i][tx + 3] = v.w;
        }
    }
    __syncthreads();
    {
        const int n  = t >> 2;        // 0..63
        const int kx = (t & 3) * 16;  // 0,16,32,48
        bf16 tmp[16];
#pragma unroll
        for (int j = 0; j < 16; j++) tmp[j] = (bf16)T[kx + j][n];
        *(bf16x8*)(dst + (size_t)(n0 + n) * K + k0 + kx)     = *(bf16x8*)&tmp[0];
        *(bf16x8*)(dst + (size_t)(n0 + n) * K + k0 + kx + 8) = *(bf16x8*)&tmp[8];
    }
}

// partial sums of c[e][d] = relu(b1[e]) . W2[e][:,d]
__global__ __launch_bounds__(256) void cpart_kernel(
    const float* __restrict__ W2, const float* __restrict__ b1,
    float* __restrict__ cpart)
{
    const int chunk = blockIdx.x;
    const int e = blockIdx.y;
    const int t = threadIdx.x;
    float acc0 = 0.f, acc1 = 0.f, acc2 = 0.f, acc3 = 0.f;
    for (int hh = 0; hh < H_DIM / 32; hh++) {
        const int h = chunk * (H_DIM / 32) + hh;
        const float rb = fmaxf(b1[(size_t)e * H_DIM + h], 0.f);
        float4 w = *(const float4*)(W2 + ((size_t)e * H_DIM + h) * D_DIM + t * 4);
        acc0 += rb * w.x; acc1 += rb * w.y; acc2 += rb * w.z; acc3 += rb * w.w;
    }
    float* dst = cpart + ((size_t)(e * 32 + chunk)) * D_DIM + t * 4;
    dst[0] = acc0; dst[1] = acc1; dst[2] = acc2; dst[3] = acc3;
}

__global__ __launch_bounds__(256) void cfinal_kernel(
    const float* __restrict__ cpart, const float* __restrict__ b2,
    float* __restrict__ adj)
{
    const int d = blockIdx.x * 256 + threadIdx.x;
    float c[E_NUM];
    float tot = 0.f;
#pragma unroll
    for (int e = 0; e < E_NUM; e++) {
        float s = 0.f;
        for (int ch = 0; ch < 32; ch++) s += cpart[((size_t)(e * 32 + ch)) * D_DIM + d];
        s += b2[(size_t)e * D_DIM + d];
        c[e] = s; tot += s;
    }
#pragma unroll
    for (int e = 0; e < E_NUM; e++) adj[(size_t)e * D_DIM + d] = tot - c[e];
}

// ---------------- grouped GEMM 1 (m97 structure): h = relu(Xg @ W1t^T + b1) ----------------
__global__ __launch_bounds__(256) void gemm1_kernel(
    const bf16* __restrict__ Xg, const bf16* __restrict__ W1t,
    const float* __restrict__ b1, const int* __restrict__ cnt,
    const int* __restrict__ off, bf16* __restrict__ Hb)
{
    const int e = blockIdx.z;
    const int ne = cnt[e];
    const int bx = blockIdx.x;
    if (bx * BM >= ne) return;
    const int by = blockIdx.y;
    const int oe = off[e];

    __shared__ bf16 As[BM * BK];
    __shared__ bf16 Bs[BN * BK];

    const int t = threadIdx.x;
    const int w = t >> 6, lane = t & 63;
    const int wr = w >> 1, wc = w & 1;
    const int lrow = lane & 15, kq = (lane >> 4) * 8;

    // staging: wave w covers tile rows [w*32, w*32+32), 2 chunks of 16 rows
    const int lr = lane >> 2;        // 0..15 row within chunk
    const int lc = (lane & 3) * 8;   // elem col within BK
    const bf16* Ast = Xg + ((size_t)(oe + bx * BM + w * 32 + lr)) * D_DIM + lc;
    const bf16* Bst = W1t + ((size_t)e * H_DIM + by * BN + w * 32 + lr) * D_DIM + lc;
    bf16* Alds = As + (w * 32) * BK;
    bf16* Blds = Bs + (w * 32) * BK;

    f32x4 acc[4][4];
#pragma unroll
    for (int m = 0; m < 4; m++)
#pragma unroll
        for (int n = 0; n < 4; n++) acc[m][n] = (f32x4){0.f, 0.f, 0.f, 0.f};

    for (int kt = 0; kt < D_DIM / BK; kt++) {
        const int kc = kt * BK;
        GLOAD16(Ast + kc,              Alds);
        GLOAD16(Ast + 16 * D_DIM + kc, Alds + 16 * BK);
        GLOAD16(Bst + kc,              Blds);
        GLOAD16(Bst + 16 * D_DIM + kc, Blds + 16 * BK);
        __syncthreads();

        bf16x8 af[4], bfr[4];
#pragma unroll
        for (int m = 0; m < 4; m++)
            af[m] = *(const bf16x8*)&As[(wr * 64 + m * 16 + lrow) * BK + kq];
#pragma unroll
        for (int n = 0; n < 4; n++)
            bfr[n] = *(const bf16x8*)&Bs[(wc * 64 + n * 16 + lrow) * BK + kq];
#pragma unroll
        for (int m = 0; m < 4; m++)
#pragma unroll
            for (int n = 0; n < 4; n++)
                acc[m][n] = __builtin_amdgcn_mfma_f32_16x16x32_bf16(af[m], bfr[n], acc[m][n], 0, 0, 0);
        __syncthreads();
    }

#pragma unroll
    for (int m = 0; m < 4; m++) {
        const int rb0 = bx * BM + wr * 64 + m * 16 + ((lane >> 4) << 2);
#pragma unroll
        for (int n = 0; n < 4; n++) {
            const int gcol = by * BN + wc * 64 + n * 16 + (lane & 15);
            const float bias = b1[(size_t)e * H_DIM + gcol];
#pragma unroll
            for (int r = 0; r < 4; r++) {
                const int grow = rb0 + r;
                if (grow < ne) {
                    float v = acc[m][n][r] + bias;
                    Hb[((size_t)(oe + grow)) * H_DIM + gcol] = (bf16)fmaxf(v, 0.f);
                }
            }
        }
    }
}

// ---------------- grouped GEMM 2 (m97 structure): out = h @ W2t^T + b2 + adj ----------------
__global__ __launch_bounds__(256) void gemm2_kernel(
    const bf16* __restrict__ Hb, const bf16* __restrict__ W2t,
    const float* __restrict__ b2, const float* __restrict__ adj,
    const int* __restrict__ cnt, const int* __restrict__ off,
    const int* __restrict__ list, float* __restrict__ out)
{
    const int e = blockIdx.z;
    const int ne = cnt[e];
    const int bx = blockIdx.x;
    if (bx * BM >= ne) return;
    const int by = blockIdx.y;
    const int oe = off[e];

    __shared__ bf16 As[BM * BK];
    __shared__ bf16 Bs[BN * BK];

    const int t = threadIdx.x;
    const int w = t >> 6, lane = t & 63;
    const int wr = w >> 1, wc = w & 1;
    const int lrow = lane & 15, kq = (lane >> 4) * 8;

    const int lr = lane >> 2;
    const int lc = (lane & 3) * 8;
    const bf16* Ast = Hb + ((size_t)(oe + bx * BM + w * 32 + lr)) * H_DIM + lc;
    const bf16* Bst = W2t + ((size_t)e * D_DIM + by * BN + w * 32 + lr) * H_DIM + lc;
    bf16* Alds = As + (w * 32) * BK;
    bf16* Blds = Bs + (w * 32) * BK;

    f32x4 acc[4][4];
#pragma unroll
    for (int m = 0; m < 4; m++)
#pragma unroll
        for (int n = 0; n < 4; n++) acc[m][n] = (f32x4){0.f, 0.f, 0.f, 0.f};

    for (int kt = 0; kt < H_DIM / BK; kt++) {
        const int kc = kt * BK;
        GLOAD16(Ast + kc,              Alds);
        GLOAD16(Ast + 16 * H_DIM + kc, Alds + 16 * BK);
        GLOAD16(Bst + kc,              Blds);
        GLOAD16(Bst + 16 * H_DIM + kc, Blds + 16 * BK);
        __syncthreads();

        bf16x8 af[4], bfr[4];
#pragma unroll
        for (int m = 0; m < 4; m++)
            af[m] = *(const bf16x8*)&As[(wr * 64 + m * 16 + lrow) * BK + kq];
#pragma unroll
        for (int n = 0; n < 4; n++)
            bfr[n] = *(const bf16x8*)&Bs[(wc * 64 + n * 16 + lrow) * BK + kq];
#pragma unroll
        for (int m = 0; m < 4; m++)
#pragma unroll
            for (int n = 0; n < 4; n++)
                acc[m][n] = __builtin_amdgcn_mfma_f32_16x16x32_bf16(af[m], bfr[n], acc[m][n], 0, 0, 0);
        __syncthreads();
    }

#pragma unroll
    for (int m = 0; m < 4; m++) {
        const int rb0 = bx * BM + wr * 64 + m * 16 + ((lane >> 4) << 2);
#pragma unroll
        for (int n = 0; n < 4; n++) {
            const int gcol = by * BN + wc * 64 + n * 16 + (lane & 15);
            const float badj = b2[(size_t)e * D_DIM + gcol] + adj[(size_t)e * D_DIM + gcol];
#pragma unroll
            for (int r = 0; r < 4; r++) {
                const int grow = rb0 + r;
                if (grow < ne) {
                    const int tok = list[e * NTOK + grow];
                    out[(size_t)tok * D_DIM + gcol] = acc[m][n][r] + badj;
                }
            }
        }
    }
}

extern "C" void kernel_launch(void* const* d_in, const int* in_sizes, int n_in,
                              void* d_out, int out_size, void* d_ws, size_t ws_size,
                              hipStream_t stream)
{
    (void)in_sizes; (void)n_in; (void)out_size; (void)ws_size;
    const float* x  = (const float*)d_in[0];
    const float* Wg = (const float*)d_in[1];
    const float* bg = (const float*)d_in[2];
    const float* W1 = (const float*)d_in[3];
    const float* b1 = (const float*)d_in[4];
    const float* W2 = (const float*)d_in[5];
    const float* b2 = (const float*)d_in[6];

    float* out_comb  = (float*)d_out;
    float* out_probs = out_comb + (size_t)NTOK * D_DIM;
    float* out_idx   = out_probs + (size_t)NTOK * E_NUM;

    // ws layout: GEMM A-staging can overread up to 127 rows past the end of
    // Xg (254 KB) and Hb (1016 KB) — both are followed by >=1.28 MB of other
    // ws buffers, so all overshoot stays inside d_ws (values unused: rows>=ne
    // are never written out).
    char* ws = (char*)d_ws;
    size_t o = 0;
    bf16* W1t = (bf16*)(ws + o); o += (size_t)E_NUM * H_DIM * D_DIM * 2;  // 64MB
    bf16* W2t = (bf16*)(ws + o); o += (size_t)E_NUM * H_DIM * D_DIM * 2;  // 64MB
    bf16* Hb  = (bf16*)(ws + o); o += (size_t)NTOK * H_DIM * 2;           // 64MB
    bf16* Xg  = (bf16*)(ws + o); o += (size_t)NTOK * D_DIM * 2;           // 16MB
    float* cpart = (float*)(ws + o); o += (size_t)E_NUM * 32 * D_DIM * 4; // 1MB
    float* adj   = (float*)(ws + o); o += (size_t)E_NUM * D_DIM * 4;      // 32KB
    int* cnt  = (int*)(ws + o); o += 256;
    int* off  = (int*)(ws + o); o += 256;
    int* list = (int*)(ws + o); o += (size_t)E_NUM * NTOK * 4;            // 256KB

    zero_cnt_kernel<<<1, 64, 0, stream>>>(cnt);
    gate_kernel<<<NTOK, 64, 0, stream>>>(x, Wg, bg, out_probs, out_idx, cnt, list);
    offsets_kernel<<<1, 64, 0, stream>>>(cnt, off);
    gather_kernel<<<NTOK, 256, 0, stream>>>(x, off, cnt, list, Xg);
    transpose_conv_kernel<<<dim3(D_DIM / 64, H_DIM / 64, E_NUM), 256, 0, stream>>>(W1, W1t, D_DIM, H_DIM);
    transpose_conv_kernel<<<dim3(H_DIM / 64, D_DIM / 64, E_NUM), 256, 0, stream>>>(W2, W2t, H_DIM, D_DIM);
    cpart_kernel<<<dim3(32, E_NUM), 256, 0, stream>>>(W2, b1, cpart);
    cfinal_kernel<<<D_DIM / 256, 256, 0, stream>>>(cpart, b2, adj);
    gemm1_kernel<<<dim3(NTOK / BM, H_DIM / BN, E_NUM), 256, 0, stream>>>(Xg, W1t, b1, cnt, off, Hb);
    gemm2_kernel<<<dim3(NTOK / BM, D_DIM / BN, E_NUM), 256, 0, stream>>>(Hb, W2t, b2, adj, cnt, off, list, out_comb);
}

// Round 3
// 543.109 us; speedup vs baseline: 1.9783x; 1.7912x over previous
//
#include <hip/hip_runtime.h>
#include <hip/hip_bf16.h>
#include <cstdint>

#define D_DIM 1024
#define H_DIM 4096
#define E_NUM 8
#define NTOK  8192

#define BM 128
#define BN 128
#define BK 32

#define NT1 72          // max row-tiles (sum ceil(ne/128) <= 64+7, padded to 72)
#define NBY1 (H_DIM / BN)   // 32
#define NBY2 (D_DIM / BN)   // 8

typedef __bf16 bf16;
typedef __bf16 bf16x8 __attribute__((ext_vector_type(8)));
typedef __bf16 bf16x4 __attribute__((ext_vector_type(4)));
typedef float  f32x4  __attribute__((ext_vector_type(4)));

// global_load_lds: per-lane global src, wave-uniform LDS base + lane*16B dest
#define GLOAD16(g, l)                                                          \
    __builtin_amdgcn_global_load_lds(                                          \
        (const __attribute__((address_space(1))) void*)(g),                    \
        (__attribute__((address_space(3))) void*)(l), 16, 0, 0)

// ---------------- gating ----------------
__global__ __launch_bounds__(64) void gate_kernel(
    const float* __restrict__ x, const float* __restrict__ Wg,
    const float* __restrict__ bg, float* __restrict__ out_probs,
    float* __restrict__ out_idx, int* __restrict__ cnt, int* __restrict__ list)
{
    const int t = blockIdx.x;
    const int l = threadIdx.x;
    double part[E_NUM];
#pragma unroll
    for (int e = 0; e < E_NUM; e++) part[e] = 0.0;
    const float* xr = x + (size_t)t * D_DIM;
#pragma unroll
    for (int i = 0; i < D_DIM / 64; i++) {
        const int d = l + i * 64;
        const float xv = xr[d];
        const float* wr = Wg + (size_t)d * E_NUM;
        float4 w0 = *(const float4*)(wr);
        float4 w1 = *(const float4*)(wr + 4);
        part[0] += (double)xv * (double)w0.x;
        part[1] += (double)xv * (double)w0.y;
        part[2] += (double)xv * (double)w0.z;
        part[3] += (double)xv * (double)w0.w;
        part[4] += (double)xv * (double)w1.x;
        part[5] += (double)xv * (double)w1.y;
        part[6] += (double)xv * (double)w1.z;
        part[7] += (double)xv * (double)w1.w;
    }
#pragma unroll
    for (int e = 0; e < E_NUM; e++) {
        double v = part[e];
        for (int s = 32; s > 0; s >>= 1) v += __shfl_xor(v, s, 64);
        part[e] = v;
    }
    if (l == 0) {
        float logits[E_NUM], probs[E_NUM];
        float m = -3.0e38f;
#pragma unroll
        for (int e = 0; e < E_NUM; e++) {
            logits[e] = (float)(part[e] + (double)bg[e]);
            m = fmaxf(m, logits[e]);
        }
        float s = 0.f;
#pragma unroll
        for (int e = 0; e < E_NUM; e++) { probs[e] = expf(logits[e] - m); s += probs[e]; }
        const float inv = 1.f / s;
        int best = 0; float bp = -1.f;
#pragma unroll
        for (int e = 0; e < E_NUM; e++) {
            probs[e] *= inv;
            if (probs[e] > bp) { bp = probs[e]; best = e; }
        }
#pragma unroll
        for (int e = 0; e < E_NUM; e++) out_probs[(size_t)t * E_NUM + e] = probs[e];
        out_idx[t] = (float)best;
        const int pos = atomicAdd(&cnt[best], 1);
        list[best * NTOK + pos] = t;
    }
}

__global__ void zero_cnt_kernel(int* cnt)
{
    if (threadIdx.x < E_NUM) cnt[threadIdx.x] = 0;
}

// prefix offsets + compact row-tile table (expert, local row0 of each 128-row tile)
__global__ void offsets_kernel(const int* __restrict__ cnt, int* __restrict__ off,
                               int* __restrict__ tile_e, int* __restrict__ tile_row,
                               int* __restrict__ tile_n)
{
    if (threadIdx.x == 0) {
        int a = 0, n = 0;
        for (int e = 0; e < E_NUM; e++) {
            off[e] = a; a += cnt[e];
            for (int rr = 0; rr < cnt[e]; rr += BM) {
                tile_e[n] = e; tile_row[n] = rr; n++;
            }
        }
        tile_n[0] = n;
    }
}

// gather routed x rows into bf16, contiguous per expert
__global__ __launch_bounds__(256) void gather_kernel(
    const float* __restrict__ x, const int* __restrict__ off,
    const int* __restrict__ cnt, const int* __restrict__ list,
    bf16* __restrict__ Xg)
{
    const int p = blockIdx.x;
    int e = 0;
    while (e < E_NUM - 1 && p >= off[e] + cnt[e]) e++;
    const int token = list[e * NTOK + (p - off[e])];
    const float* src = x + (size_t)token * D_DIM;
    bf16* dst = Xg + (size_t)p * D_DIM;
    const int t = threadIdx.x;
    float4 v = *(const float4*)(src + t * 4);
    bf16x4 o;
    o[0] = (bf16)v.x; o[1] = (bf16)v.y; o[2] = (bf16)v.z; o[3] = (bf16)v.w;
    *(bf16x4*)(dst + t * 4) = o;
}

// transpose+convert one [K][N] fp32 matrix (per expert) to [N][K] bf16. 64x64 tiles.
__global__ __launch_bounds__(256) void transpose_conv_kernel(
    const float* __restrict__ in, bf16* __restrict__ out, int K, int N)
{
    const int e = blockIdx.z;
    const float* src = in + (size_t)e * K * N;
    bf16* dst = out + (size_t)e * K * N;
    __shared__ float T[64][65];
    const int t = threadIdx.x;
    const int k0 = blockIdx.x * 64, n0 = blockIdx.y * 64;
    {
        const int ty = t >> 4;
        const int tx = (t & 15) * 4;
#pragma unroll
        for (int i = 0; i < 4; i++) {
            float4 v = *(const float4*)(src + (size_t)(k0 + ty + 16 * i) * N + n0 + tx);
            T[ty + 16 * i][tx + 0] = v.x; T[ty + 16 * i][tx + 1] = v.y;
            T[ty + 16 * i][tx + 2] = v.z; T[ty + 16 * i][tx + 3] = v.w;
        }
    }
    __syncthreads();
    {
        const int n  = t >> 2;
        const int kx = (t & 3) * 16;
        bf16 tmp[16];
#pragma unroll
        for (int j = 0; j < 16; j++) tmp[j] = (bf16)T[kx + j][n];
        *(bf16x8*)(dst + (size_t)(n0 + n) * K + k0 + kx)     = *(bf16x8*)&tmp[0];
        *(bf16x8*)(dst + (size_t)(n0 + n) * K + k0 + kx + 8) = *(bf16x8*)&tmp[8];
    }
}

// partial sums of c[e][d] = relu(b1[e]) . W2[e][:,d]
__global__ __launch_bounds__(256) void cpart_kernel(
    const float* __restrict__ W2, const float* __restrict__ b1,
    float* __restrict__ cpart)
{
    const int chunk = blockIdx.x;
    const int e = blockIdx.y;
    const int t = threadIdx.x;
    float acc0 = 0.f, acc1 = 0.f, acc2 = 0.f, acc3 = 0.f;
    for (int hh = 0; hh < H_DIM / 32; hh++) {
        const int h = chunk * (H_DIM / 32) + hh;
        const float rb = fmaxf(b1[(size_t)e * H_DIM + h], 0.f);
        float4 w = *(const float4*)(W2 + ((size_t)e * H_DIM + h) * D_DIM + t * 4);
        acc0 += rb * w.x; acc1 += rb * w.y; acc2 += rb * w.z; acc3 += rb * w.w;
    }
    float* dst = cpart + ((size_t)(e * 32 + chunk)) * D_DIM + t * 4;
    dst[0] = acc0; dst[1] = acc1; dst[2] = acc2; dst[3] = acc3;
}

__global__ __launch_bounds__(256) void cfinal_kernel(
    const float* __restrict__ cpart, const float* __restrict__ b2,
    float* __restrict__ adj)
{
    const int d = blockIdx.x * 256 + threadIdx.x;
    float c[E_NUM];
    float tot = 0.f;
#pragma unroll
    for (int e = 0; e < E_NUM; e++) {
        float s = 0.f;
        for (int ch = 0; ch < 32; ch++) s += cpart[((size_t)(e * 32 + ch)) * D_DIM + d];
        s += b2[(size_t)e * D_DIM + d];
        c[e] = s; tot += s;
    }
#pragma unroll
    for (int e = 0; e < E_NUM; e++) adj[(size_t)e * D_DIM + d] = tot - c[e];
}

// ---------------- grouped GEMM 1: h = relu(Xg @ W1t^T + b1) ----------------
// 1-D compact grid: fid = by*NT1 + tx (tx inner), m204 bijective XCD swizzle.
__global__ __launch_bounds__(256) void gemm1_kernel(
    const bf16* __restrict__ Xg, const bf16* __restrict__ W1t,
    const float* __restrict__ b1, const int* __restrict__ cnt,
    const int* __restrict__ off, const int* __restrict__ tile_e,
    const int* __restrict__ tile_row, const int* __restrict__ tile_n,
    bf16* __restrict__ Hb)
{
    const int orig = blockIdx.x;
    const int q = (NT1 * NBY1) >> 3;           // 2304/8, divisible by 8
    const int fid = (orig & 7) * q + (orig >> 3);
    const int tx = fid % NT1;
    const int by = fid / NT1;
    if (tx >= tile_n[0]) return;
    const int e  = tile_e[tx];
    const int m0 = tile_row[tx];
    const int ne = cnt[e];
    const int oe = off[e];

    __shared__ bf16 As[BM * BK];
    __shared__ bf16 Bs[BN * BK];

    const int t = threadIdx.x;
    const int w = t >> 6, lane = t & 63;
    const int wr = w >> 1, wc = w & 1;
    const int lrow = lane & 15, kq = (lane >> 4) * 8;

    const int lr = lane >> 2;
    const int lc = (lane & 3) * 8;
    const bf16* Ast = Xg + ((size_t)(oe + m0 + w * 32 + lr)) * D_DIM + lc;
    const bf16* Bst = W1t + ((size_t)e * H_DIM + by * BN + w * 32 + lr) * D_DIM + lc;
    bf16* Alds = As + (w * 32) * BK;
    bf16* Blds = Bs + (w * 32) * BK;

    f32x4 acc[4][4];
#pragma unroll
    for (int m = 0; m < 4; m++)
#pragma unroll
        for (int n = 0; n < 4; n++) acc[m][n] = (f32x4){0.f, 0.f, 0.f, 0.f};

    for (int kt = 0; kt < D_DIM / BK; kt++) {
        const int kc = kt * BK;
        GLOAD16(Ast + kc,              Alds);
        GLOAD16(Ast + 16 * D_DIM + kc, Alds + 16 * BK);
        GLOAD16(Bst + kc,              Blds);
        GLOAD16(Bst + 16 * D_DIM + kc, Blds + 16 * BK);
        __syncthreads();

        bf16x8 af[4], bfr[4];
#pragma unroll
        for (int m = 0; m < 4; m++)
            af[m] = *(const bf16x8*)&As[(wr * 64 + m * 16 + lrow) * BK + kq];
#pragma unroll
        for (int n = 0; n < 4; n++)
            bfr[n] = *(const bf16x8*)&Bs[(wc * 64 + n * 16 + lrow) * BK + kq];
#pragma unroll
        for (int m = 0; m < 4; m++)
#pragma unroll
            for (int n = 0; n < 4; n++)
                acc[m][n] = __builtin_amdgcn_mfma_f32_16x16x32_bf16(af[m], bfr[n], acc[m][n], 0, 0, 0);
        __syncthreads();
    }

#pragma unroll
    for (int m = 0; m < 4; m++) {
        const int rb0 = m0 + wr * 64 + m * 16 + ((lane >> 4) << 2);
#pragma unroll
        for (int n = 0; n < 4; n++) {
            const int gcol = by * BN + wc * 64 + n * 16 + (lane & 15);
            const float bias = b1[(size_t)e * H_DIM + gcol];
#pragma unroll
            for (int r = 0; r < 4; r++) {
                const int grow = rb0 + r;
                if (grow < ne) {
                    float v = acc[m][n][r] + bias;
                    Hb[((size_t)(oe + grow)) * H_DIM + gcol] = (bf16)fmaxf(v, 0.f);
                }
            }
        }
    }
}

// ---------------- grouped GEMM 2: out = h @ W2t^T + b2 + adj ----------------
__global__ __launch_bounds__(256) void gemm2_kernel(
    const bf16* __restrict__ Hb, const bf16* __restrict__ W2t,
    const float* __restrict__ b2, const float* __restrict__ adj,
    const int* __restrict__ cnt, const int* __restrict__ off,
    const int* __restrict__ tile_e, const int* __restrict__ tile_row,
    const int* __restrict__ tile_n, const int* __restrict__ list,
    float* __restrict__ out)
{
    const int orig = blockIdx.x;
    const int q = (NT1 * NBY2) >> 3;           // 576/8, divisible by 8
    const int fid = (orig & 7) * q + (orig >> 3);
    const int tx = fid % NT1;
    const int by = fid / NT1;
    if (tx >= tile_n[0]) return;
    const int e  = tile_e[tx];
    const int m0 = tile_row[tx];
    const int ne = cnt[e];
    const int oe = off[e];

    __shared__ bf16 As[BM * BK];
    __shared__ bf16 Bs[BN * BK];

    const int t = threadIdx.x;
    const int w = t >> 6, lane = t & 63;
    const int wr = w >> 1, wc = w & 1;
    const int lrow = lane & 15, kq = (lane >> 4) * 8;

    const int lr = lane >> 2;
    const int lc = (lane & 3) * 8;
    const bf16* Ast = Hb + ((size_t)(oe + m0 + w * 32 + lr)) * H_DIM + lc;
    const bf16* Bst = W2t + ((size_t)e * D_DIM + by * BN + w * 32 + lr) * H_DIM + lc;
    bf16* Alds = As + (w * 32) * BK;
    bf16* Blds = Bs + (w * 32) * BK;

    f32x4 acc[4][4];
#pragma unroll
    for (int m = 0; m < 4; m++)
#pragma unroll
        for (int n = 0; n < 4; n++) acc[m][n] = (f32x4){0.f, 0.f, 0.f, 0.f};

    for (int kt = 0; kt < H_DIM / BK; kt++) {
        const int kc = kt * BK;
        GLOAD16(Ast + kc,              Alds);
        GLOAD16(Ast + 16 * H_DIM + kc, Alds + 16 * BK);
        GLOAD16(Bst + kc,              Blds);
        GLOAD16(Bst + 16 * H_DIM + kc, Blds + 16 * BK);
        __syncthreads();

        bf16x8 af[4], bfr[4];
#pragma unroll
        for (int m = 0; m < 4; m++)
            af[m] = *(const bf16x8*)&As[(wr * 64 + m * 16 + lrow) * BK + kq];
#pragma unroll
        for (int n = 0; n < 4; n++)
            bfr[n] = *(const bf16x8*)&Bs[(wc * 64 + n * 16 + lrow) * BK + kq];
#pragma unroll
        for (int m = 0; m < 4; m++)
#pragma unroll
            for (int n = 0; n < 4; n++)
                acc[m][n] = __builtin_amdgcn_mfma_f32_16x16x32_bf16(af[m], bfr[n], acc[m][n], 0, 0, 0);
        __syncthreads();
    }

#pragma unroll
    for (int m = 0; m < 4; m++) {
        const int rb0 = m0 + wr * 64 + m * 16 + ((lane >> 4) << 2);
#pragma unroll
        for (int n = 0; n < 4; n++) {
            const int gcol = by * BN + wc * 64 + n * 16 + (lane & 15);
            const float badj = b2[(size_t)e * D_DIM + gcol] + adj[(size_t)e * D_DIM + gcol];
#pragma unroll
            for (int r = 0; r < 4; r++) {
                const int grow = rb0 + r;
                if (grow < ne) {
                    const int tok = list[e * NTOK + grow];
                    out[(size_t)tok * D_DIM + gcol] = acc[m][n][r] + badj;
                }
            }
        }
    }
}

extern "C" void kernel_launch(void* const* d_in, const int* in_sizes, int n_in,
                              void* d_out, int out_size, void* d_ws, size_t ws_size,
                              hipStream_t stream)
{
    (void)in_sizes; (void)n_in; (void)out_size; (void)ws_size;
    const float* x  = (const float*)d_in[0];
    const float* Wg = (const float*)d_in[1];
    const float* bg = (const float*)d_in[2];
    const float* W1 = (const float*)d_in[3];
    const float* b1 = (const float*)d_in[4];
    const float* W2 = (const float*)d_in[5];
    const float* b2 = (const float*)d_in[6];

    float* out_comb  = (float*)d_out;
    float* out_probs = out_comb + (size_t)NTOK * D_DIM;
    float* out_idx   = out_probs + (size_t)NTOK * E_NUM;

    // ws layout: GEMM A-staging can overread up to 127 rows past the end of
    // Xg (254 KB) and Hb (1016 KB) — both are followed by >=1 MB of other
    // ws buffers, so all overshoot stays inside d_ws (values unused: rows>=ne
    // are never written out).
    char* ws = (char*)d_ws;
    size_t o = 0;
    bf16* W1t = (bf16*)(ws + o); o += (size_t)E_NUM * H_DIM * D_DIM * 2;  // 64MB
    bf16* W2t = (bf16*)(ws + o); o += (size_t)E_NUM * H_DIM * D_DIM * 2;  // 64MB
    bf16* Hb  = (bf16*)(ws + o); o += (size_t)NTOK * H_DIM * 2;           // 64MB
    bf16* Xg  = (bf16*)(ws + o); o += (size_t)NTOK * D_DIM * 2;           // 16MB
    float* cpart = (float*)(ws + o); o += (size_t)E_NUM * 32 * D_DIM * 4; // 1MB
    float* adj   = (float*)(ws + o); o += (size_t)E_NUM * D_DIM * 4;      // 32KB
    int* cnt  = (int*)(ws + o); o += 256;
    int* off  = (int*)(ws + o); o += 256;
    int* tile_e   = (int*)(ws + o); o += 512;
    int* tile_row = (int*)(ws + o); o += 512;
    int* tile_n   = (int*)(ws + o); o += 256;
    int* list = (int*)(ws + o); o += (size_t)E_NUM * NTOK * 4;            // 256KB

    zero_cnt_kernel<<<1, 64, 0, stream>>>(cnt);
    gate_kernel<<<NTOK, 64, 0, stream>>>(x, Wg, bg, out_probs, out_idx, cnt, list);
    offsets_kernel<<<1, 64, 0, stream>>>(cnt, off, tile_e, tile_row, tile_n);
    gather_kernel<<<NTOK, 256, 0, stream>>>(x, off, cnt, list, Xg);
    transpose_conv_kernel<<<dim3(D_DIM / 64, H_DIM / 64, E_NUM), 256, 0, stream>>>(W1, W1t, D_DIM, H_DIM);
    transpose_conv_kernel<<<dim3(H_DIM / 64, D_DIM / 64, E_NUM), 256, 0, stream>>>(W2, W2t, H_DIM, D_DIM);
    cpart_kernel<<<dim3(32, E_NUM), 256, 0, stream>>>(W2, b1, cpart);
    cfinal_kernel<<<D_DIM / 256, 256, 0, stream>>>(cpart, b2, adj);
    gemm1_kernel<<<NT1 * NBY1, 256, 0, stream>>>(Xg, W1t, b1, cnt, off, tile_e, tile_row, tile_n, Hb);
    gemm2_kernel<<<NT1 * NBY2, 256, 0, stream>>>(Hb, W2t, b2, adj, cnt, off, tile_e, tile_row, tile_n, list, out_comb);
}